// Round 2
// baseline (523.806 us; speedup 1.0000x reference)
//
#include <hip/hip_runtime.h>

// ---------------------------------------------------------------------------
// Res_NL pansharpening network, B=1, H=W=128. All inputs/outputs are float32
// (per reference dtypes). Pipeline in f32:
//   features_k : uf/pf 3x3 convs + all nine 1x1 transforms -> phi/theta/g maps
//   heads_k    : 3 windowed-attention heads (7x7 window, 3x3/1x1 patches)
//   assemble_k : mlp combine + resu/respan convs -> x[42ch]
//   conv3_k    : 6 res-block convs + recon conv
// ---------------------------------------------------------------------------

#define DEV __device__ __forceinline__

constexpr int N = 128 * 128;   // 16384 pixels

// ---- workspace layout (float offsets) -------------------------------------
constexpr int OFF_PHI1 =   0 * N;   // 3 ch
constexpr int OFF_TH1  =   3 * N;   // 3 ch
constexpr int OFF_PHI2 =   6 * N;   // 5 ch
constexpr int OFF_TH2  =  11 * N;   // 5 ch
constexpr int OFF_PHI3 =  16 * N;   // 8 ch
constexpr int OFF_TH3  =  24 * N;   // 8 ch
constexpr int OFF_G1   =  32 * N;   // 5 ch
constexpr int OFF_G2   =  37 * N;   // 5 ch
constexpr int OFF_G3   =  42 * N;   // 5 ch
constexpr int OFF_X    =  47 * N;   // 42 ch
// OH buffers overlap F: OH live only between heads_k and assemble_k;
// F first written by the res-block conv afterwards.
constexpr int OFF_OH1  =  89 * N;   // 5 ch
constexpr int OFF_OH2  =  94 * N;   // 5 ch
constexpr int OFF_OH3  =  99 * N;   // 5 ch
constexpr int OFF_F    =  89 * N;   // 42 ch (res-block temp)
// total ws use: 131*N*4 = 8.59 MB

DEV bool inb(int y, int x) { return (unsigned)y < 128u && (unsigned)x < 128u; }

// ---------------------------------------------------------------------------
// K1: uf/pf (3x3 convs) + all 1x1 transforms -> phi/theta/g maps (47 ch)
// ---------------------------------------------------------------------------
__global__ __launch_bounds__(256) void features_k(
    const float* __restrict__ u, const float* __restrict__ pan,
    const float* __restrict__ wnlu, const float* __restrict__ wnlpan,
    const float* __restrict__ gphi, const float* __restrict__ gth,
    const float* __restrict__ gg, const float* __restrict__ sphi,
    const float* __restrict__ sth, const float* __restrict__ sg,
    const float* __restrict__ mphi, const float* __restrict__ mth,
    const float* __restrict__ mg, float* __restrict__ ws) {
    const int p = blockIdx.x * 256 + threadIdx.x;
    const int y = p >> 7, x = p & 127;

    float uf[5] = {0, 0, 0, 0, 0};
    for (int ic = 0; ic < 8; ++ic) {
#pragma unroll
        for (int i = 0; i < 3; ++i) {
            int yy = y + i - 1;
#pragma unroll
            for (int j = 0; j < 3; ++j) {
                int xx = x + j - 1;
                float v = inb(yy, xx) ? u[ic * N + yy * 128 + xx] : 0.f;
#pragma unroll
                for (int o = 0; o < 5; ++o)
                    uf[o] = fmaf(v, wnlu[(o * 8 + ic) * 9 + i * 3 + j], uf[o]);
            }
        }
    }
    float pf[3] = {0, 0, 0};
#pragma unroll
    for (int i = 0; i < 3; ++i) {
        int yy = y + i - 1;
#pragma unroll
        for (int j = 0; j < 3; ++j) {
            int xx = x + j - 1;
            float v = inb(yy, xx) ? pan[yy * 128 + xx] : 0.f;
#pragma unroll
            for (int o = 0; o < 3; ++o)
                pf[o] = fmaf(v, wnlpan[o * 9 + i * 3 + j], pf[o]);
        }
    }
    float cat[8] = {uf[0], uf[1], uf[2], uf[3], uf[4], pf[0], pf[1], pf[2]};

#pragma unroll
    for (int o = 0; o < 3; ++o) {
        float a = 0, b = 0;
#pragma unroll
        for (int i = 0; i < 3; ++i) {
            a = fmaf(gphi[o * 3 + i], pf[i], a);
            b = fmaf(gth [o * 3 + i], pf[i], b);
        }
        ws[OFF_PHI1 + o * N + p] = a;
        ws[OFF_TH1  + o * N + p] = b;
    }
#pragma unroll
    for (int o = 0; o < 5; ++o) {
        float a = 0, b = 0, c1 = 0, c2 = 0, c3 = 0;
#pragma unroll
        for (int i = 0; i < 5; ++i) {
            a  = fmaf(sphi[o * 5 + i], uf[i], a);
            b  = fmaf(sth [o * 5 + i], uf[i], b);
            c1 = fmaf(gg  [o * 5 + i], uf[i], c1);
            c2 = fmaf(sg  [o * 5 + i], uf[i], c2);
            c3 = fmaf(mg  [o * 5 + i], uf[i], c3);
        }
        ws[OFF_PHI2 + o * N + p] = a;
        ws[OFF_TH2  + o * N + p] = b;
        ws[OFF_G1   + o * N + p] = c1;
        ws[OFF_G2   + o * N + p] = c2;
        ws[OFF_G3   + o * N + p] = c3;
    }
#pragma unroll
    for (int o = 0; o < 8; ++o) {
        float a = 0, b = 0;
#pragma unroll
        for (int i = 0; i < 8; ++i) {
            a = fmaf(mphi[o * 8 + i], cat[i], a);
            b = fmaf(mth [o * 8 + i], cat[i], b);
        }
        ws[OFF_PHI3 + o * N + p] = a;
        ws[OFF_TH3  + o * N + p] = b;
    }
}

// ---------------------------------------------------------------------------
// K2: attention heads.
//   score_k = <unfold_P(theta)@x , unfold_P(phi)@(x+off_k)>
// Semantics (matches nested unfold in reference):
//   - patch elements individually zero-padded at image boundary
//   - whole patch = 0 when the window-neighbor CENTER is out of image
//     (score 0 still enters the softmax)
//   - g value = 0 for out-of-image neighbors in the PV product
// ---------------------------------------------------------------------------
template <int C, int P>
DEV void head_body(const float* __restrict__ phi, const float* __restrict__ theta,
                   const float* __restrict__ g, float* __restrict__ oh, int p) {
    const int y = p >> 7, x = p & 127;
    constexpr int PR = P / 2;
    constexpr int W  = 7 + 2 * PR;

    float s[49];
#pragma unroll
    for (int k = 0; k < 49; ++k) s[k] = 0.f;

    for (int c = 0; c < C; ++c) {
        const float* phc = phi + c * N;
        const float* thc = theta + c * N;
        float T[P][P];
#pragma unroll
        for (int i = 0; i < P; ++i)
#pragma unroll
            for (int j = 0; j < P; ++j) {
                int yy = y + i - PR, xx = x + j - PR;
                T[i][j] = inb(yy, xx) ? thc[yy * 128 + xx] : 0.f;
            }
        // sliding band of phi rows covering patch rows of the current
        // neighbor row d; reuse across the 7 neighbor columns
        float R[P][W];
#pragma unroll
        for (int r = 0; r < P; ++r) {
            int yy = y - 3 - PR + r;
#pragma unroll
            for (int t = 0; t < W; ++t) {
                int xx = x - 3 - PR + t;
                R[r][t] = inb(yy, xx) ? phc[yy * 128 + xx] : 0.f;
            }
        }
#pragma unroll
        for (int d = 0; d < 7; ++d) {
#pragma unroll
            for (int dx = 0; dx < 7; ++dx) {
                float a = 0.f;
#pragma unroll
                for (int i = 0; i < P; ++i)
#pragma unroll
                    for (int j = 0; j < P; ++j)
                        a = fmaf(T[i][j], R[i][dx + j], a);
                s[d * 7 + dx] += a;
            }
            if (d < 6) {
#pragma unroll
                for (int r = 0; r < P - 1; ++r)
#pragma unroll
                    for (int t = 0; t < W; ++t) R[r][t] = R[r + 1][t];
                int yy = y - 3 - PR + d + P;
#pragma unroll
                for (int t = 0; t < W; ++t) {
                    int xx = x - 3 - PR + t;
                    R[P - 1][t] = inb(yy, xx) ? phc[yy * 128 + xx] : 0.f;
                }
            }
        }
    }
    // zero scores whose window-neighbor center is out of image
#pragma unroll
    for (int k = 0; k < 49; ++k) {
        int qy = y + k / 7 - 3, qx = x + (k % 7) - 3;
        if (!inb(qy, qx)) s[k] = 0.f;
    }
    float m = s[0];
#pragma unroll
    for (int k = 1; k < 49; ++k) m = fmaxf(m, s[k]);
    float den = 0.f;
#pragma unroll
    for (int k = 0; k < 49; ++k) { float e = __expf(s[k] - m); s[k] = e; den += e; }

    float o[5] = {0, 0, 0, 0, 0};
#pragma unroll
    for (int k = 0; k < 49; ++k) {
        int qy = y + k / 7 - 3, qx = x + (k % 7) - 3;
        bool ok = inb(qy, qx);
        int base = qy * 128 + qx;
#pragma unroll
        for (int c5 = 0; c5 < 5; ++c5) {
            float gv = ok ? g[c5 * N + base] : 0.f;
            o[c5] = fmaf(s[k], gv, o[c5]);
        }
    }
    float inv = 1.f / den;
#pragma unroll
    for (int c5 = 0; c5 < 5; ++c5) oh[c5 * N + p] = o[c5] * inv;
}

__global__ __launch_bounds__(64) void heads_k(float* __restrict__ ws) {
    const int p = blockIdx.x * 64 + threadIdx.x;
    if (blockIdx.y == 0)
        head_body<3, 3>(ws + OFF_PHI1, ws + OFF_TH1, ws + OFF_G1, ws + OFF_OH1, p);
    else if (blockIdx.y == 1)
        head_body<5, 1>(ws + OFF_PHI2, ws + OFF_TH2, ws + OFF_G2, ws + OFF_OH2, p);
    else
        head_body<8, 3>(ws + OFF_PHI3, ws + OFF_TH3, ws + OFF_G3, ws + OFF_OH3, p);
}

// ---------------------------------------------------------------------------
// K3: x[0..5) = mlp-combined attention; x[5..37) = conv(u,w_resu);
//     x[37..42) = conv(pan,w_respan)
// ---------------------------------------------------------------------------
__global__ __launch_bounds__(256) void assemble_k(
    const float* __restrict__ u, const float* __restrict__ pan,
    const float* __restrict__ wres, const float* __restrict__ wrp,
    const float* __restrict__ mlpw, const float* __restrict__ mlpb,
    float* __restrict__ ws) {
    const int p = blockIdx.x * 256 + threadIdx.x;
    const int y = p >> 7, x = p & 127;
    float* xb = ws + OFF_X;

    const float w0 = mlpw[0], w1 = mlpw[1], w2 = mlpw[2];
    const float bb = mlpb[0];
#pragma unroll
    for (int c = 0; c < 5; ++c) {
        float a = ws[OFF_OH1 + c * N + p] * w0 + ws[OFF_OH2 + c * N + p] * w1 +
                  ws[OFF_OH3 + c * N + p] * w2 + bb;
        xb[c * N + p] = a;
    }
    // resu: 8 -> 32
    float acc[32];
#pragma unroll
    for (int o = 0; o < 32; ++o) acc[o] = 0.f;
    for (int ic = 0; ic < 8; ++ic) {
#pragma unroll
        for (int i = 0; i < 3; ++i) {
            int yy = y + i - 1;
#pragma unroll
            for (int j = 0; j < 3; ++j) {
                int xx = x + j - 1;
                float v = inb(yy, xx) ? u[ic * N + yy * 128 + xx] : 0.f;
#pragma unroll
                for (int o = 0; o < 32; ++o)
                    acc[o] = fmaf(v, wres[(o * 8 + ic) * 9 + i * 3 + j], acc[o]);
            }
        }
    }
#pragma unroll
    for (int o = 0; o < 32; ++o) xb[(5 + o) * N + p] = acc[o];
    // respan: 1 -> 5
    float a5[5] = {0, 0, 0, 0, 0};
#pragma unroll
    for (int i = 0; i < 3; ++i) {
        int yy = y + i - 1;
#pragma unroll
        for (int j = 0; j < 3; ++j) {
            int xx = x + j - 1;
            float v = inb(yy, xx) ? pan[yy * 128 + xx] : 0.f;
#pragma unroll
            for (int o = 0; o < 5; ++o)
                a5[o] = fmaf(v, wrp[o * 9 + i * 3 + j], a5[o]);
        }
    }
#pragma unroll
    for (int o = 0; o < 5; ++o) xb[(37 + o) * N + p] = a5[o];
}

// ---------------------------------------------------------------------------
// Generic direct 3x3 conv: thread = pixel, OCG output channels per thread.
// Weight index is block-uniform -> scalar loads. grid = (N/256, COUT/OCG).
// ---------------------------------------------------------------------------
template <int CIN, int OCG, bool BIAS, bool RELU, bool SKIP>
__global__ __launch_bounds__(256) void conv3_k(const float* __restrict__ in,
                                               const float* __restrict__ wt,
                                               const float* __restrict__ bs,
                                               const float* __restrict__ skip,
                                               float* __restrict__ outp) {
    const int p = blockIdx.x * 256 + threadIdx.x;
    const int y = p >> 7, x = p & 127;
    const int ocb = blockIdx.y * OCG;
    float acc[OCG];
#pragma unroll
    for (int i = 0; i < OCG; ++i) acc[i] = 0.f;

    for (int ic = 0; ic < CIN; ++ic) {
#pragma unroll
        for (int i = 0; i < 3; ++i) {
            int yy = y + i - 1;
            bool ry = (unsigned)yy < 128u;
#pragma unroll
            for (int j = 0; j < 3; ++j) {
                int xx = x + j - 1;
                bool ok = ry && ((unsigned)xx < 128u);
                float v = ok ? in[ic * N + yy * 128 + xx] : 0.f;
#pragma unroll
                for (int oc = 0; oc < OCG; ++oc)
                    acc[oc] = fmaf(v, wt[((ocb + oc) * CIN + ic) * 9 + i * 3 + j], acc[oc]);
            }
        }
    }
#pragma unroll
    for (int oc = 0; oc < OCG; ++oc) {
        float r = acc[oc];
        if (BIAS) r += bs[ocb + oc];
        if (SKIP) r += skip[(ocb + oc) * N + p];
        if (RELU) r = fmaxf(r, 0.f);
        outp[(ocb + oc) * N + p] = r;
    }
}

// ---------------------------------------------------------------------------
extern "C" void kernel_launch(void* const* d_in, const int* in_sizes, int n_in,
                              void* d_out, int out_size, void* d_ws, size_t ws_size,
                              hipStream_t stream) {
    (void)in_sizes; (void)n_in; (void)out_size; (void)ws_size;
    float* ws = (float*)d_ws;
    float* out = (float*)d_out;

    const float* u      = (const float*)d_in[0];
    const float* pan    = (const float*)d_in[1];
    const float* wnlu   = (const float*)d_in[2];
    const float* wnlpan = (const float*)d_in[3];
    const float* gphi   = (const float*)d_in[4];
    const float* gth    = (const float*)d_in[5];
    const float* gg     = (const float*)d_in[6];
    const float* sphi   = (const float*)d_in[7];
    const float* sth    = (const float*)d_in[8];
    const float* sg     = (const float*)d_in[9];
    const float* mphi   = (const float*)d_in[10];
    const float* mth    = (const float*)d_in[11];
    const float* mg     = (const float*)d_in[12];
    const float* mlpw   = (const float*)d_in[13];
    const float* mlpb   = (const float*)d_in[14];
    const float* wres   = (const float*)d_in[15];
    const float* wrp    = (const float*)d_in[16];
    const float* wrecon = (const float*)d_in[17];

    features_k<<<N / 256, 256, 0, stream>>>(u, pan, wnlu, wnlpan, gphi, gth, gg,
                                            sphi, sth, sg, mphi, mth, mg, ws);
    heads_k<<<dim3(N / 64, 3), 64, 0, stream>>>(ws);
    assemble_k<<<N / 256, 256, 0, stream>>>(u, pan, wres, wrp, mlpw, mlpb, ws);

    for (int r = 0; r < 3; ++r) {
        const float* w1 = (const float*)d_in[18 + 4 * r];
        const float* b1 = (const float*)d_in[19 + 4 * r];
        const float* w2 = (const float*)d_in[20 + 4 * r];
        const float* b2 = (const float*)d_in[21 + 4 * r];
        // f = relu(conv(x, w1) + b1)
        conv3_k<42, 7, true, true, false>
            <<<dim3(N / 256, 6), 256, 0, stream>>>(ws + OFF_X, w1, b1, nullptr,
                                                   ws + OFF_F);
        // x = relu(conv(f, w2) + b2 + x)
        conv3_k<42, 7, true, true, true>
            <<<dim3(N / 256, 6), 256, 0, stream>>>(ws + OFF_F, w2, b2, ws + OFF_X,
                                                   ws + OFF_X);
    }
    // recon: 42 -> 8
    conv3_k<42, 4, false, false, false>
        <<<dim3(N / 256, 2), 256, 0, stream>>>(ws + OFF_X, wrecon, nullptr,
                                               nullptr, out);
}